// Round 3
// baseline (297.070 us; speedup 1.0000x reference)
//
#include <hip/hip_runtime.h>

typedef unsigned short u16;
typedef unsigned int u32;
typedef unsigned long long u64;
typedef float f32x4 __attribute__((ext_vector_type(4)));
typedef __bf16 bf16x8 __attribute__((ext_vector_type(8)));

#define NU 4096
#define DD 256
#define BB 8192

__device__ inline u16 f2b(float f) {
    u32 u = __builtin_bit_cast(u32, f);
    u32 r = (u + 0x7fffu + ((u >> 16) & 1u)) >> 16;
    return (u16)r;
}
__device__ inline float lrelu(float x) { return x > 0.f ? x : 0.2f * x; }

#define BARRIER_LGKM() asm volatile("s_waitcnt lgkmcnt(0)\ns_barrier" ::: "memory")

// ============ prologue: conv(x_u,x_i) + tconv(user,item,pred1) + uvec + wprod ============
__global__ __launch_bounds__(256) void k_pro(
    const float* __restrict__ x_u, const float* __restrict__ x_i,
    const float* __restrict__ user_W, const float* __restrict__ item_W, const float* __restrict__ pred_W1,
    const float* __restrict__ soc_W, const float* __restrict__ soc_a,
    const float* __restrict__ cnt_W, const float* __restrict__ cnt_a,
    const float* __restrict__ user_b, const float* __restrict__ item_b,
    u16* __restrict__ xu_b, u16* __restrict__ xi_b,
    u16* __restrict__ uWt, u16* __restrict__ iWt, u16* __restrict__ p1Wt,
    float* __restrict__ uvec,
    u16* __restrict__ WusT, u16* __restrict__ WicT,
    float* __restrict__ b_us, float* __restrict__ b_ic) {
    __shared__ float t[64][65];
    __shared__ float sa[256];
    const int b = blockIdx.x;
    const int tid = threadIdx.x;

    if (b < 1024) {  // f32 -> bf16 convert
        const float* in = (b < 512) ? x_u : x_i;
        u16* out = (b < 512) ? xu_b : xi_b;
        int i = (b & 511) * 256 + tid;
        const float4 v0 = *(const float4*)(in + (size_t)i * 8);
        const float4 v1 = *(const float4*)(in + (size_t)i * 8 + 4);
        u16 u[8] = {f2b(v0.x), f2b(v0.y), f2b(v0.z), f2b(v0.w),
                    f2b(v1.x), f2b(v1.y), f2b(v1.z), f2b(v1.w)};
        *(uint4*)(out + (size_t)i * 8) = *(uint4*)u;
    } else if (b < 1088) {  // transpose-convert weights
        int j = b - 1024;
        const float* in;
        u16* out;
        int R;
        if (j < 16) { in = user_W; out = uWt; R = 256; }
        else if (j < 32) { in = item_W; out = iWt; R = 256; j -= 16; }
        else { in = pred_W1; out = p1Wt; R = 512; j -= 32; }
        int rb = (j >> 2) * 64, cb = (j & 3) * 64;
        for (int k = 0; k < 16; ++k) {
            int idx = k * 256 + tid;
            int lr = idx >> 6, lc = idx & 63;
            t[lr][lc] = in[(size_t)(rb + lr) * 256 + cb + lc];
        }
        __syncthreads();
        for (int k = 0; k < 16; ++k) {
            int idx = k * 256 + tid;
            int lr = idx >> 6, lc = idx & 63;
            out[(size_t)(cb + lr) * R + rb + lc] = f2b(t[lc][lr]);
        }
    } else if (b < 1092) {  // uvec: u[b][in] = sum_out W[in][out]*a_half[out]
        int bb = b - 1088;
        const float* W = (bb < 2) ? soc_W : cnt_W;
        const float* a = ((bb < 2) ? soc_a : cnt_a) + (bb & 1) * 256;
        int lane = tid & 63, wv = tid >> 6;
        sa[tid] = a[tid];
        __syncthreads();
        for (int rr = 0; rr < 64; ++rr) {
            int in = wv * 64 + rr;
            float4 w4 = *(const float4*)(W + (size_t)in * 256 + lane * 4);
            float acc = w4.x * sa[lane * 4] + w4.y * sa[lane * 4 + 1] + w4.z * sa[lane * 4 + 2] + w4.w * sa[lane * 4 + 3];
#pragma unroll
            for (int off = 32; off; off >>= 1) acc += __shfl_down(acc, off);
            if (lane == 0) uvec[bb * 256 + in] = acc;
        }
    } else {  // wprod: C = A@B (256x256x256), store C^T bf16; bias = bvec@B
        int j = b - 1092;
        int p = j >> 4;
        int tile = j & 15;
        const float* A = p ? item_W : user_W;
        const float* Bw = p ? cnt_W : soc_W;
        const float* bvec = p ? item_b : user_b;
        u16* outT = p ? WicT : WusT;
        float* outb = p ? b_ic : b_us;
        int m0 = (tile >> 2) * 64, n0 = (tile & 3) * 64;
        int m = m0 + (tid >> 4) * 4, n = n0 + (tid & 15) * 4;
        float acc[4][4];
#pragma unroll
        for (int i = 0; i < 4; ++i)
#pragma unroll
            for (int k = 0; k < 4; ++k) acc[i][k] = 0.f;
        for (int k0 = 0; k0 < 256; k0 += 4) {
            float aa[4][4], bb2[4][4];
#pragma unroll
            for (int i = 0; i < 4; ++i) {
                float4 v = *(const float4*)(A + (size_t)(m + i) * 256 + k0);
                aa[i][0] = v.x; aa[i][1] = v.y; aa[i][2] = v.z; aa[i][3] = v.w;
            }
#pragma unroll
            for (int k = 0; k < 4; ++k) {
                float4 v = *(const float4*)(Bw + (size_t)(k0 + k) * 256 + n);
                bb2[k][0] = v.x; bb2[k][1] = v.y; bb2[k][2] = v.z; bb2[k][3] = v.w;
            }
#pragma unroll
            for (int i = 0; i < 4; ++i)
#pragma unroll
                for (int k = 0; k < 4; ++k)
#pragma unroll
                    for (int jj = 0; jj < 4; ++jj) acc[i][jj] += aa[i][k] * bb2[k][jj];
        }
#pragma unroll
        for (int i = 0; i < 4; ++i)
#pragma unroll
            for (int jj = 0; jj < 4; ++jj) outT[(size_t)(n + jj) * 256 + m + i] = f2b(acc[i][jj]);
        if (tile >> 2 == 0 && tid < 64) {
            int nn = n0 + tid;
            float s = 0.f;
            for (int k = 0; k < 256; ++k) s += bvec[k] * Bw[(size_t)k * 256 + nn];
            outb[nn] = s;
        }
    }
}

// ============ z=4 feature GEMMs: h_u, h_i(+bf16), WhT, WiT ============
__global__ __launch_bounds__(256) void k_gemm4(
    const u16* __restrict__ xu_b, const u16* __restrict__ xi_b,
    const u16* __restrict__ uWt, const u16* __restrict__ iWt,
    const u16* __restrict__ WusT, const u16* __restrict__ WicT,
    const float* __restrict__ user_b, const float* __restrict__ item_b,
    const float* __restrict__ b_us, const float* __restrict__ b_ic,
    float* __restrict__ h_u_f, float* __restrict__ h_i_f, u16* __restrict__ h_i_b,
    u16* __restrict__ WhT, u16* __restrict__ WiT) {
    const int z = blockIdx.z;
    const int M = 4096, N = 256, K = 256;
    const u16* A = (z == 0 || z == 2) ? xu_b : xi_b;
    const u16* Bt = (z == 0) ? uWt : (z == 1) ? iWt : (z == 2) ? WusT : WicT;
    const float* bias = (z == 0) ? user_b : (z == 1) ? item_b : (z == 2) ? b_us : b_ic;
    float* Cf = (z == 0) ? h_u_f : (z == 1) ? h_i_f : nullptr;
    u16* Cb = (z == 1) ? h_i_b : nullptr;
    u16* Cbt = (z == 2) ? WhT : (z == 3) ? WiT : nullptr;

    __shared__ u16 As[64 * 64];
    __shared__ u16 Bs[64 * 64];
    const int tid = threadIdx.x;
    const int lane = tid & 63, wv = tid >> 6;
    const int bm = blockIdx.x * 64, bn = blockIdx.y * 64;
    const int wm = (wv >> 1) * 32, wn = (wv & 1) * 32;
    f32x4 acc[2][2];
#pragma unroll
    for (int i = 0; i < 2; i++)
#pragma unroll
        for (int j = 0; j < 2; j++) acc[i][j] = f32x4{0.f, 0.f, 0.f, 0.f};

    char* Ab = (char*)As;
    char* Bb = (char*)Bs;
    const int r = tid >> 2;
    const int ib0 = (tid & 3) * 32;
    const int swz = (r & 7) << 4;

    for (int k0 = 0; k0 < K; k0 += 64) {
        const uint4* ga = (const uint4*)(A + (size_t)(bm + r) * K + k0 + (ib0 >> 1));
        const uint4* gb = (const uint4*)(Bt + (size_t)(bn + r) * K + k0 + (ib0 >> 1));
        uint4 va0 = ga[0], va1 = ga[1];
        uint4 vb0 = gb[0], vb1 = gb[1];
        __syncthreads();
        *(uint4*)(Ab + r * 128 + ((ib0) ^ swz)) = va0;
        *(uint4*)(Ab + r * 128 + ((ib0 + 16) ^ swz)) = va1;
        *(uint4*)(Bb + r * 128 + ((ib0) ^ swz)) = vb0;
        *(uint4*)(Bb + r * 128 + ((ib0 + 16) ^ swz)) = vb1;
        __syncthreads();
#pragma unroll
        for (int kh = 0; kh < 2; ++kh) {
            bf16x8 af[2], bfr[2];
#pragma unroll
            for (int mf = 0; mf < 2; ++mf) {
                int row = wm + mf * 16 + (lane & 15);
                int kb = kh * 64 + ((lane >> 4) << 4);
                af[mf] = *(const bf16x8*)(Ab + row * 128 + (kb ^ ((row & 7) << 4)));
            }
#pragma unroll
            for (int nf = 0; nf < 2; ++nf) {
                int row = wn + nf * 16 + (lane & 15);
                int kb = kh * 64 + ((lane >> 4) << 4);
                bfr[nf] = *(const bf16x8*)(Bb + row * 128 + (kb ^ ((row & 7) << 4)));
            }
#pragma unroll
            for (int mf = 0; mf < 2; ++mf)
#pragma unroll
                for (int nf = 0; nf < 2; ++nf)
                    acc[mf][nf] = __builtin_amdgcn_mfma_f32_16x16x32_bf16(af[mf], bfr[nf], acc[mf][nf], 0, 0, 0);
        }
    }
#pragma unroll
    for (int mf = 0; mf < 2; ++mf) {
#pragma unroll
        for (int nf = 0; nf < 2; ++nf) {
            int col = bn + wn + nf * 16 + (lane & 15);
            int row0 = bm + wm + mf * 16 + ((lane >> 4) << 2);
            float bv = bias[col];
            float v[4];
#pragma unroll
            for (int q = 0; q < 4; ++q) {
                float x = acc[mf][nf][q] + bv;
                v[q] = x;
                if (Cf) Cf[(size_t)(row0 + q) * N + col] = x;
                if (Cb) Cb[(size_t)(row0 + q) * N + col] = f2b(x);
            }
            if (Cbt) {
                uint2 p;
                p.x = (u32)f2b(v[0]) | ((u32)f2b(v[1]) << 16);
                p.y = (u32)f2b(v[2]) | ((u32)f2b(v[3]) << 16);
                *(uint2*)(Cbt + (size_t)col * M + row0) = p;
            }
        }
    }
}

// ============ a-vector GEMVs ============
__global__ __launch_bounds__(256) void k_gemv_a(const float* __restrict__ h_u, const float* __restrict__ h_i,
                                                const float* __restrict__ uvec, float* __restrict__ avec) {
    int tid = threadIdx.x, lane = tid & 63, wv = tid >> 6;
    int ib = blockIdx.x * 64;
    const float* H = (wv == 3) ? h_i : h_u;
    const float* u = uvec + wv * 256;
    float4 u4 = *(const float4*)(u + lane * 4);
    for (int rr = 0; rr < 64; ++rr) {
        int row = ib + rr;
        float4 h4 = *(const float4*)(H + (size_t)row * 256 + lane * 4);
        float acc = h4.x * u4.x + h4.y * u4.y + h4.z * u4.z + h4.w * u4.w;
#pragma unroll
        for (int off = 32; off; off >>= 1) acc += __shfl_down(acc, off);
        if (lane == 0) avec[wv * 4096 + row] = acc;
    }
}

// ============ fused GAT: scan + softmax + alpha write + msg MFMA, one pass ============
// block = 32 rows x 4096 cols, 8 waves, grid (128, 2)
__global__ __launch_bounds__(512) void k_flash(const int* __restrict__ adjS, const int* __restrict__ adjC,
                                               const float* __restrict__ avec,
                                               const u16* __restrict__ WhT, const u16* __restrict__ WiT,
                                               float* __restrict__ out, float* __restrict__ msg) {
    const int z = blockIdx.y;
    const int ib = blockIdx.x * 32;
    const int tid = threadIdx.x, lane = tid & 63, wv = tid >> 6;
    const int* adj = z ? adjC : adjS;
    const float* a1 = avec + z * 8192;
    const float* a2 = a1 + 4096;
    const u16* Pt = z ? WiT : WhT;
    float* alpha = out + 8192 + (size_t)z * 16777216;
    float* msgz = msg + (size_t)z * 4096 * 256;

    __shared__ float a2s[4096];
    __shared__ u64 bitsl[32][64];
    __shared__ u16 Atile[2][2048];
    __shared__ float s_a1[32], s_mr[32], s_inv[32];
    __shared__ float redw[8];

    // stage a2 + in-block global max
    float lmax = -1e30f;
    for (int c = tid; c < 4096; c += 512) {
        float v = a2[c];
        a2s[c] = v;
        lmax = fmaxf(lmax, v);
    }
#pragma unroll
    for (int off = 32; off; off >>= 1) lmax = fmaxf(lmax, __shfl_down(lmax, off));
    if (lane == 0) redw[wv] = lmax;
    __syncthreads();
    float mh = redw[0];
#pragma unroll
    for (int w = 1; w < 8; ++w) mh = fmaxf(mh, redw[w]);

    // ---- phase 1: stream adj, pack bits to LDS, accumulate denominators ----
    const int r0 = wv * 4;
    float a1v[4], mrv[4], accv[4];
#pragma unroll
    for (int q = 0; q < 4; ++q) {
        a1v[q] = a1[ib + r0 + q];
        mrv[q] = lrelu(a1v[q] + mh);
        accv[q] = 0.f;
    }
#pragma unroll 4
    for (int jc = 0; jc < 64; ++jc) {
        float a2v = a2s[jc * 64 + lane];
#pragma unroll
        for (int q = 0; q < 4; ++q) {
            int ad = adj[(size_t)(ib + r0 + q) * 4096 + jc * 64 + lane];
            float e = __expf(lrelu(a1v[q] + a2v) - mrv[q]);
            bool m = ad != 0;
            accv[q] += m ? e : 0.f;
            u64 bal = __ballot(m);
            if (lane == 0) bitsl[r0 + q][jc] = bal;
        }
    }
#pragma unroll
    for (int q = 0; q < 4; ++q) {
        float d = accv[q];
#pragma unroll
        for (int off = 32; off; off >>= 1) d += __shfl_down(d, off);
        if (lane == 0) {
            s_a1[r0 + q] = a1v[q];
            s_mr[r0 + q] = mrv[q];
            s_inv[r0 + q] = d > 0.f ? 1.f / d : 0.f;
        }
    }
    __syncthreads();

    // ---- phase 2: alpha write + MFMA (double-buffered LDS tile, 1 lgkm-barrier/chunk) ----
    const int prow = tid >> 4, sub = tid & 15;
    const float pa1 = s_a1[prow], pmr = s_mr[prow], piv = s_inv[prow];
    const int gr = ib + prow;
    const int pswz = (prow & 7) << 4;
    char* Ab = (char*)Atile;

    f32x4 acc[2][2];
#pragma unroll
    for (int i = 0; i < 2; i++)
#pragma unroll
        for (int j = 0; j < 2; j++) acc[i][j] = f32x4{0.f, 0.f, 0.f, 0.f};

    auto compute_tile = [&](int jc, int buf) {
        float4 a2v = *(const float4*)(a2s + jc * 64 + sub * 4);
        u32 nib = (u32)((bitsl[prow][jc] >> (sub * 4)) & 15ull);
        float aa[4] = {a2v.x, a2v.y, a2v.z, a2v.w};
        float al[4];
#pragma unroll
        for (int k = 0; k < 4; ++k) {
            float e = __expf(lrelu(pa1 + aa[k]) - pmr);
            al[k] = ((nib >> k) & 1) ? e * piv : 0.f;
        }
        *(float4*)(alpha + (size_t)gr * 4096 + jc * 64 + sub * 4) = *(float4*)al;
        u16 pk[4] = {f2b(al[0]), f2b(al[1]), f2b(al[2]), f2b(al[3])};
        *(uint2*)(Ab + buf * 4096 + prow * 128 + ((sub * 8) ^ pswz)) = *(uint2*)pk;
    };

    compute_tile(0, 0);
    BARRIER_LGKM();
    const int n0 = wv * 32;
    for (int jc = 0; jc < 64; ++jc) {
        const int buf = jc & 1;
        if (jc < 63) compute_tile(jc + 1, buf ^ 1);
#pragma unroll
        for (int ks = 0; ks < 2; ++ks) {
            bf16x8 bfr[2];
#pragma unroll
            for (int nf = 0; nf < 2; ++nf)
                bfr[nf] = *(const bf16x8*)(Pt + (size_t)(n0 + nf * 16 + (lane & 15)) * 4096 + jc * 64 + ks * 32 + ((lane >> 4) << 3));
#pragma unroll
            for (int mf = 0; mf < 2; ++mf) {
                int ra = mf * 16 + (lane & 15);
                bf16x8 af = *(const bf16x8*)(Ab + buf * 4096 + ra * 128 + ((ks * 64 + ((lane >> 4) << 4)) ^ ((ra & 7) << 4)));
#pragma unroll
                for (int nf = 0; nf < 2; ++nf)
                    acc[mf][nf] = __builtin_amdgcn_mfma_f32_16x16x32_bf16(af, bfr[nf], acc[mf][nf], 0, 0, 0);
            }
        }
        BARRIER_LGKM();
    }

#pragma unroll
    for (int mf = 0; mf < 2; ++mf) {
        int rr = mf * 16 + ((lane >> 4) << 2);
#pragma unroll
        for (int nf = 0; nf < 2; ++nf) {
            int col = n0 + nf * 16 + (lane & 15);
#pragma unroll
            for (int q = 0; q < 4; ++q) msgz[(size_t)(ib + rr + q) * 256 + col] = acc[mf][nf][q];
        }
    }
}

// ============ post: elu(soc+cnt+h_u) + gate ============
__global__ __launch_bounds__(256) void k_post(const float* __restrict__ msg, const float* __restrict__ h_u,
                                              const float* __restrict__ q_u,
                                              const float* __restrict__ gate_W, const float* __restrict__ gate_b,
                                              const float* __restrict__ qproj_W, const float* __restrict__ qproj_b,
                                              const float* __restrict__ alpha_q, u16* __restrict__ huo_b) {
    int i = blockIdx.x;
    int n = threadIdx.x;
    float s = msg[(size_t)i * 256 + n] + msg[(size_t)(4096 + i) * 256 + n];
    float v = s + h_u[(size_t)i * 256 + n];
    v = v > 0.f ? v : expm1f(v);
    float q0 = q_u[i * 4 + 0], q1 = q_u[i * 4 + 1], q2 = q_u[i * 4 + 2], q3 = q_u[i * 4 + 3];
    float g = q0 * gate_W[n] + q1 * gate_W[256 + n] + q2 * gate_W[512 + n] + q3 * gate_W[768 + n] + gate_b[n];
    g = 1.f / (1.f + __expf(-g));
    float qp = q0 * qproj_W[n] + q1 * qproj_W[256 + n] + q2 * qproj_W[512 + n] + q3 * qproj_W[768 + n] + qproj_b[n];
    float o = v + alpha_q[0] * g * qp;
    huo_b[(size_t)i * 256 + n] = f2b(o);
}

// ============ pred: gathered GEMM (B=8192, K=512, N=256) + fused r_hat ============
__global__ __launch_bounds__(512) void k_pred(const u16* __restrict__ huo_b, const u16* __restrict__ h_i_b,
                                              const int* __restrict__ uidx, const int* __restrict__ iidx,
                                              const u16* __restrict__ Bt, const float* __restrict__ b1,
                                              const float* __restrict__ W2, const float* __restrict__ b2,
                                              float* __restrict__ out) {
    __shared__ u16 As[64 * 512];
    __shared__ float redL[512];
    const int tid = threadIdx.x, lane = tid & 63, wv = tid >> 6;
    const int bm = blockIdx.x * 64;
    char* Ab = (char*)As;

    // stage gathered A: 64 rows x 512 cols bf16, swizzled
    {
        const int r = tid >> 3;
        const int uix = uidx[bm + r], iix = iidx[bm + r];
        const int sswz = (r & 7) << 4;
#pragma unroll
        for (int c = 0; c < 8; ++c) {
            int e = c * 64 + (tid & 7) * 8;
            const u16* src = (e < 256) ? (huo_b + (size_t)uix * 256 + e) : (h_i_b + (size_t)iix * 256 + (e - 256));
            uint4 v = *(const uint4*)src;
            *(uint4*)(Ab + r * 1024 + ((e * 2) ^ sswz)) = v;
        }
    }
    __syncthreads();

    const int n0 = wv * 32;
    f32x4 acc[4][2];
#pragma unroll
    for (int i = 0; i < 4; i++)
#pragma unroll
        for (int j = 0; j < 2; j++) acc[i][j] = f32x4{0.f, 0.f, 0.f, 0.f};

    for (int ks = 0; ks < 16; ++ks) {
        bf16x8 bfr[2];
#pragma unroll
        for (int nf = 0; nf < 2; ++nf)
            bfr[nf] = *(const bf16x8*)(Bt + (size_t)(n0 + nf * 16 + (lane & 15)) * 512 + ks * 32 + ((lane >> 4) << 3));
#pragma unroll
        for (int mf = 0; mf < 4; ++mf) {
            int ra = mf * 16 + (lane & 15);
            bf16x8 af = *(const bf16x8*)(Ab + ra * 1024 + ((ks * 64 + ((lane >> 4) << 4)) ^ ((ra & 7) << 4)));
#pragma unroll
            for (int nf = 0; nf < 2; ++nf)
                acc[mf][nf] = __builtin_amdgcn_mfma_f32_16x16x32_bf16(af, bfr[nf], acc[mf][nf], 0, 0, 0);
        }
    }

    // fused epilogue: r = sum_col relu(hid+b1)*W2
    float b1v[2], w2v[2];
#pragma unroll
    for (int nf = 0; nf < 2; ++nf) {
        int col = n0 + nf * 16 + (lane & 15);
        b1v[nf] = b1[col];
        w2v[nf] = W2[col];
    }
#pragma unroll
    for (int mf = 0; mf < 4; ++mf) {
#pragma unroll
        for (int q = 0; q < 4; ++q) {
            float val = 0.f;
#pragma unroll
            for (int nf = 0; nf < 2; ++nf) val += fmaxf(acc[mf][nf][q] + b1v[nf], 0.f) * w2v[nf];
#pragma unroll
            for (int off = 1; off < 16; off <<= 1) val += __shfl_xor(val, off);
            if ((lane & 15) == 0) redL[wv * 64 + mf * 16 + ((lane >> 4) << 2) + q] = val;
        }
    }
    __syncthreads();
    if (tid < 64) {
        float r = b2[0];
#pragma unroll
        for (int w = 0; w < 8; ++w) r += redL[w * 64 + tid];
        out[bm + tid] = 1.f + 4.f / (1.f + __expf(-r));
    }
}

extern "C" void kernel_launch(void* const* d_in, const int* in_sizes, int n_in,
                              void* d_out, int out_size, void* d_ws, size_t ws_size,
                              hipStream_t stream) {
    const float* x_u = (const float*)d_in[0];
    const float* x_i = (const float*)d_in[1];
    const int* adjS = (const int*)d_in[2];
    const int* adjC = (const int*)d_in[3];
    const int* uidx = (const int*)d_in[4];
    const int* iidx = (const int*)d_in[5];
    const float* q_u = (const float*)d_in[6];
    const float* user_W = (const float*)d_in[7];
    const float* user_b = (const float*)d_in[8];
    const float* item_W = (const float*)d_in[9];
    const float* item_b = (const float*)d_in[10];
    const float* soc_W = (const float*)d_in[11];
    const float* soc_a = (const float*)d_in[12];
    const float* cnt_W = (const float*)d_in[13];
    const float* cnt_a = (const float*)d_in[14];
    const float* gate_W = (const float*)d_in[15];
    const float* gate_b = (const float*)d_in[16];
    const float* qproj_W = (const float*)d_in[17];
    const float* qproj_b = (const float*)d_in[18];
    const float* alpha_q = (const float*)d_in[19];
    const float* pred_W1 = (const float*)d_in[20];
    const float* pred_b1 = (const float*)d_in[21];
    const float* pred_W2 = (const float*)d_in[22];
    const float* pred_b2 = (const float*)d_in[23];
    float* out = (float*)d_out;

    char* w = (char*)d_ws;
    size_t off = 0;
    auto alloc = [&](size_t bytes) -> void* {
        void* p = w + off;
        off = (off + bytes + 255) & ~(size_t)255;
        return p;
    };
    u16* xu_b = (u16*)alloc((size_t)NU * DD * 2);
    u16* xi_b = (u16*)alloc((size_t)NU * DD * 2);
    u16* uWt = (u16*)alloc(256 * 256 * 2);
    u16* iWt = (u16*)alloc(256 * 256 * 2);
    u16* p1Wt = (u16*)alloc(512 * 256 * 2);
    u16* WusT = (u16*)alloc(256 * 256 * 2);
    u16* WicT = (u16*)alloc(256 * 256 * 2);
    float* b_us = (float*)alloc(256 * 4);
    float* b_ic = (float*)alloc(256 * 4);
    float* uvec = (float*)alloc(4 * 256 * 4);
    float* h_u_f = (float*)alloc((size_t)NU * DD * 4);
    float* h_i_f = (float*)alloc((size_t)NU * DD * 4);
    u16* h_i_b = (u16*)alloc((size_t)NU * DD * 2);
    u16* WhT = (u16*)alloc((size_t)NU * DD * 2);
    u16* WiT = (u16*)alloc((size_t)NU * DD * 2);
    float* avec = (float*)alloc(4 * 4096 * 4);
    float* msg = (float*)alloc((size_t)2 * 4096 * 256 * 4);
    u16* huo_b = (u16*)alloc((size_t)NU * DD * 2);
    (void)in_sizes; (void)n_in; (void)out_size; (void)ws_size;

    k_pro<<<1124, 256, 0, stream>>>(x_u, x_i, user_W, item_W, pred_W1, soc_W, soc_a, cnt_W, cnt_a,
                                    user_b, item_b, xu_b, xi_b, uWt, iWt, p1Wt, uvec, WusT, WicT, b_us, b_ic);
    k_gemm4<<<dim3(64, 4, 4), 256, 0, stream>>>(xu_b, xi_b, uWt, iWt, WusT, WicT, user_b, item_b, b_us, b_ic,
                                                h_u_f, h_i_f, h_i_b, WhT, WiT);
    k_gemv_a<<<64, 256, 0, stream>>>(h_u_f, h_i_f, uvec, avec);
    k_flash<<<dim3(128, 2), 512, 0, stream>>>(adjS, adjC, avec, WhT, WiT, out, msg);
    k_post<<<4096, 256, 0, stream>>>(msg, h_u_f, q_u, gate_W, gate_b, qproj_W, qproj_b, alpha_q, huo_b);
    k_pred<<<128, 512, 0, stream>>>(huo_b, h_i_b, uidx, iidx, p1Wt, pred_b1, pred_W2, pred_b2, out);
}

// Round 4
// 202.917 us; speedup vs baseline: 1.4640x; 1.4640x over previous
//
#include <hip/hip_runtime.h>

typedef unsigned short u16;
typedef unsigned int u32;
typedef unsigned char u8;
typedef unsigned long long u64;
typedef float f32x4 __attribute__((ext_vector_type(4)));
typedef __bf16 bf16x8 __attribute__((ext_vector_type(8)));

#define NU 4096
#define DD 256
#define BB 8192

__device__ inline u16 f2b(float f) {
    u32 u = __builtin_bit_cast(u32, f);
    u32 r = (u + 0x7fffu + ((u >> 16) & 1u)) >> 16;
    return (u16)r;
}
__device__ inline float lrelu(float x) { return x > 0.f ? x : 0.2f * x; }

#define BARRIER_LGKM() asm volatile("s_waitcnt lgkmcnt(0)\ns_barrier" ::: "memory")

// ============ prologue: conv(x_u,x_i) + tconv(user,item,pred1) + uvec + wprod ============
__global__ __launch_bounds__(256) void k_pro(
    const float* __restrict__ x_u, const float* __restrict__ x_i,
    const float* __restrict__ user_W, const float* __restrict__ item_W, const float* __restrict__ pred_W1,
    const float* __restrict__ soc_W, const float* __restrict__ soc_a,
    const float* __restrict__ cnt_W, const float* __restrict__ cnt_a,
    const float* __restrict__ user_b, const float* __restrict__ item_b,
    u16* __restrict__ xu_b, u16* __restrict__ xi_b,
    u16* __restrict__ uWt, u16* __restrict__ iWt, u16* __restrict__ p1Wt,
    float* __restrict__ uvec,
    u16* __restrict__ WusT, u16* __restrict__ WicT,
    float* __restrict__ b_us, float* __restrict__ b_ic) {
    __shared__ float t[64][65];
    __shared__ float sa[256];
    const int b = blockIdx.x;
    const int tid = threadIdx.x;

    if (b < 1024) {  // f32 -> bf16 convert
        const float* in = (b < 512) ? x_u : x_i;
        u16* out = (b < 512) ? xu_b : xi_b;
        int i = (b & 511) * 256 + tid;
        const float4 v0 = *(const float4*)(in + (size_t)i * 8);
        const float4 v1 = *(const float4*)(in + (size_t)i * 8 + 4);
        u16 u[8] = {f2b(v0.x), f2b(v0.y), f2b(v0.z), f2b(v0.w),
                    f2b(v1.x), f2b(v1.y), f2b(v1.z), f2b(v1.w)};
        *(uint4*)(out + (size_t)i * 8) = *(uint4*)u;
    } else if (b < 1088) {  // transpose-convert weights
        int j = b - 1024;
        const float* in;
        u16* out;
        int R;
        if (j < 16) { in = user_W; out = uWt; R = 256; }
        else if (j < 32) { in = item_W; out = iWt; R = 256; j -= 16; }
        else { in = pred_W1; out = p1Wt; R = 512; j -= 32; }
        int rb = (j >> 2) * 64, cb = (j & 3) * 64;
        for (int k = 0; k < 16; ++k) {
            int idx = k * 256 + tid;
            int lr = idx >> 6, lc = idx & 63;
            t[lr][lc] = in[(size_t)(rb + lr) * 256 + cb + lc];
        }
        __syncthreads();
        for (int k = 0; k < 16; ++k) {
            int idx = k * 256 + tid;
            int lr = idx >> 6, lc = idx & 63;
            out[(size_t)(cb + lr) * R + rb + lc] = f2b(t[lc][lr]);
        }
    } else if (b < 1092) {  // uvec
        int bb = b - 1088;
        const float* W = (bb < 2) ? soc_W : cnt_W;
        const float* a = ((bb < 2) ? soc_a : cnt_a) + (bb & 1) * 256;
        int lane = tid & 63, wv = tid >> 6;
        sa[tid] = a[tid];
        __syncthreads();
        for (int rr = 0; rr < 64; ++rr) {
            int in = wv * 64 + rr;
            float4 w4 = *(const float4*)(W + (size_t)in * 256 + lane * 4);
            float acc = w4.x * sa[lane * 4] + w4.y * sa[lane * 4 + 1] + w4.z * sa[lane * 4 + 2] + w4.w * sa[lane * 4 + 3];
#pragma unroll
            for (int off = 32; off; off >>= 1) acc += __shfl_down(acc, off);
            if (lane == 0) uvec[bb * 256 + in] = acc;
        }
    } else {  // wprod: C = A@B (256x256x256), store C^T bf16; bias = bvec@B
        int j = b - 1092;
        int p = j >> 4;
        int tile = j & 15;
        const float* A = p ? item_W : user_W;
        const float* Bw = p ? cnt_W : soc_W;
        const float* bvec = p ? item_b : user_b;
        u16* outT = p ? WicT : WusT;
        float* outb = p ? b_ic : b_us;
        int m0 = (tile >> 2) * 64, n0 = (tile & 3) * 64;
        int m = m0 + (tid >> 4) * 4, n = n0 + (tid & 15) * 4;
        float acc[4][4];
#pragma unroll
        for (int i = 0; i < 4; ++i)
#pragma unroll
            for (int k = 0; k < 4; ++k) acc[i][k] = 0.f;
        for (int k0 = 0; k0 < 256; k0 += 4) {
            float aa[4][4], bb2[4][4];
#pragma unroll
            for (int i = 0; i < 4; ++i) {
                float4 v = *(const float4*)(A + (size_t)(m + i) * 256 + k0);
                aa[i][0] = v.x; aa[i][1] = v.y; aa[i][2] = v.z; aa[i][3] = v.w;
            }
#pragma unroll
            for (int k = 0; k < 4; ++k) {
                float4 v = *(const float4*)(Bw + (size_t)(k0 + k) * 256 + n);
                bb2[k][0] = v.x; bb2[k][1] = v.y; bb2[k][2] = v.z; bb2[k][3] = v.w;
            }
#pragma unroll
            for (int i = 0; i < 4; ++i)
#pragma unroll
                for (int k = 0; k < 4; ++k)
#pragma unroll
                    for (int jj = 0; jj < 4; ++jj) acc[i][jj] += aa[i][k] * bb2[k][jj];
        }
#pragma unroll
        for (int i = 0; i < 4; ++i)
#pragma unroll
            for (int jj = 0; jj < 4; ++jj) outT[(size_t)(n + jj) * 256 + m + i] = f2b(acc[i][jj]);
        if (tile >> 2 == 0 && tid < 64) {
            int nn = n0 + tid;
            float s = 0.f;
            for (int k = 0; k < 256; ++k) s += bvec[k] * Bw[(size_t)k * 256 + nn];
            outb[nn] = s;
        }
    }
}

// ============ z=4 feature GEMMs: h_u, h_i(+bf16), WhT, WiT ============
__global__ __launch_bounds__(256) void k_gemm4(
    const u16* __restrict__ xu_b, const u16* __restrict__ xi_b,
    const u16* __restrict__ uWt, const u16* __restrict__ iWt,
    const u16* __restrict__ WusT, const u16* __restrict__ WicT,
    const float* __restrict__ user_b, const float* __restrict__ item_b,
    const float* __restrict__ b_us, const float* __restrict__ b_ic,
    float* __restrict__ h_u_f, float* __restrict__ h_i_f, u16* __restrict__ h_i_b,
    u16* __restrict__ WhT, u16* __restrict__ WiT) {
    const int z = blockIdx.z;
    const int M = 4096, N = 256, K = 256;
    const u16* A = (z == 0 || z == 2) ? xu_b : xi_b;
    const u16* Bt = (z == 0) ? uWt : (z == 1) ? iWt : (z == 2) ? WusT : WicT;
    const float* bias = (z == 0) ? user_b : (z == 1) ? item_b : (z == 2) ? b_us : b_ic;
    float* Cf = (z == 0) ? h_u_f : (z == 1) ? h_i_f : nullptr;
    u16* Cb = (z == 1) ? h_i_b : nullptr;
    u16* Cbt = (z == 2) ? WhT : (z == 3) ? WiT : nullptr;

    __shared__ u16 As[64 * 64];
    __shared__ u16 Bs[64 * 64];
    const int tid = threadIdx.x;
    const int lane = tid & 63, wv = tid >> 6;
    const int bm = blockIdx.x * 64, bn = blockIdx.y * 64;
    const int wm = (wv >> 1) * 32, wn = (wv & 1) * 32;
    f32x4 acc[2][2];
#pragma unroll
    for (int i = 0; i < 2; i++)
#pragma unroll
        for (int j = 0; j < 2; j++) acc[i][j] = f32x4{0.f, 0.f, 0.f, 0.f};

    char* Ab = (char*)As;
    char* Bb = (char*)Bs;
    const int r = tid >> 2;
    const int ib0 = (tid & 3) * 32;
    const int swz = (r & 7) << 4;

    for (int k0 = 0; k0 < K; k0 += 64) {
        const uint4* ga = (const uint4*)(A + (size_t)(bm + r) * K + k0 + (ib0 >> 1));
        const uint4* gb = (const uint4*)(Bt + (size_t)(bn + r) * K + k0 + (ib0 >> 1));
        uint4 va0 = ga[0], va1 = ga[1];
        uint4 vb0 = gb[0], vb1 = gb[1];
        __syncthreads();
        *(uint4*)(Ab + r * 128 + ((ib0) ^ swz)) = va0;
        *(uint4*)(Ab + r * 128 + ((ib0 + 16) ^ swz)) = va1;
        *(uint4*)(Bb + r * 128 + ((ib0) ^ swz)) = vb0;
        *(uint4*)(Bb + r * 128 + ((ib0 + 16) ^ swz)) = vb1;
        __syncthreads();
#pragma unroll
        for (int kh = 0; kh < 2; ++kh) {
            bf16x8 af[2], bfr[2];
#pragma unroll
            for (int mf = 0; mf < 2; ++mf) {
                int row = wm + mf * 16 + (lane & 15);
                int kb = kh * 64 + ((lane >> 4) << 4);
                af[mf] = *(const bf16x8*)(Ab + row * 128 + (kb ^ ((row & 7) << 4)));
            }
#pragma unroll
            for (int nf = 0; nf < 2; ++nf) {
                int row = wn + nf * 16 + (lane & 15);
                int kb = kh * 64 + ((lane >> 4) << 4);
                bfr[nf] = *(const bf16x8*)(Bb + row * 128 + (kb ^ ((row & 7) << 4)));
            }
#pragma unroll
            for (int mf = 0; mf < 2; ++mf)
#pragma unroll
                for (int nf = 0; nf < 2; ++nf)
                    acc[mf][nf] = __builtin_amdgcn_mfma_f32_16x16x32_bf16(af[mf], bfr[nf], acc[mf][nf], 0, 0, 0);
        }
    }
#pragma unroll
    for (int mf = 0; mf < 2; ++mf) {
#pragma unroll
        for (int nf = 0; nf < 2; ++nf) {
            int col = bn + wn + nf * 16 + (lane & 15);
            int row0 = bm + wm + mf * 16 + ((lane >> 4) << 2);
            float bv = bias[col];
            float v[4];
#pragma unroll
            for (int q = 0; q < 4; ++q) {
                float x = acc[mf][nf][q] + bv;
                v[q] = x;
                if (Cf) Cf[(size_t)(row0 + q) * N + col] = x;
                if (Cb) Cb[(size_t)(row0 + q) * N + col] = f2b(x);
            }
            if (Cbt) {
                uint2 p;
                p.x = (u32)f2b(v[0]) | ((u32)f2b(v[1]) << 16);
                p.y = (u32)f2b(v[2]) | ((u32)f2b(v[3]) << 16);
                *(uint2*)(Cbt + (size_t)col * M + row0) = p;
            }
        }
    }
}

// ============ a-vector GEMVs ============
__global__ __launch_bounds__(256) void k_gemv_a(const float* __restrict__ h_u, const float* __restrict__ h_i,
                                                const float* __restrict__ uvec, float* __restrict__ avec) {
    int tid = threadIdx.x, lane = tid & 63, wv = tid >> 6;
    int ib = blockIdx.x * 64;
    const float* H = (wv == 3) ? h_i : h_u;
    const float* u = uvec + wv * 256;
    float4 u4 = *(const float4*)(u + lane * 4);
    for (int rr = 0; rr < 64; ++rr) {
        int row = ib + rr;
        float4 h4 = *(const float4*)(H + (size_t)row * 256 + lane * 4);
        float acc = h4.x * u4.x + h4.y * u4.y + h4.z * u4.z + h4.w * u4.w;
#pragma unroll
        for (int off = 32; off; off >>= 1) acc += __shfl_down(acc, off);
        if (lane == 0) avec[wv * 4096 + row] = acc;
    }
}

__global__ __launch_bounds__(256) void k_maxfinal(const float* __restrict__ avec, float* __restrict__ Mh) {
    __shared__ float red[256];
    int t = threadIdx.x;
    for (int z = 0; z < 2; ++z) {
        const float* a2 = avec + z * 8192 + 4096;
        float m = -1e30f;
        for (int i = t; i < 4096; i += 256) m = fmaxf(m, a2[i]);
        red[t] = m;
        __syncthreads();
        for (int s = 128; s; s >>= 1) {
            if (t < s) red[t] = fmaxf(red[t], red[t + s]);
            __syncthreads();
        }
        if (t == 0) Mh[z] = red[0];
        __syncthreads();
    }
}

// ============ denom scan + bit-pack adjacency (1 bit/edge) ============
__global__ __launch_bounds__(256) void k_scan(const int* __restrict__ adjS, const int* __restrict__ adjC,
                                              const float* __restrict__ avec, const float* __restrict__ Mh,
                                              float* __restrict__ dpart, u8* __restrict__ bits) {
    int z = blockIdx.z;
    const int* adj = z ? adjC : adjS;
    const float* a1 = avec + z * 8192;
    const float* a2 = a1 + 4096;
    u8* bz = bits + (size_t)z * 2097152;
    float mhg = Mh[z];
    int ib = blockIdx.x * 64, jb = blockIdx.y * 512;
    int lane = threadIdx.x & 63, wv = threadIdx.x >> 6;
    float4 A0 = *(const float4*)(a2 + jb + lane * 8);
    float4 A1 = *(const float4*)(a2 + jb + lane * 8 + 4);
    for (int rr = 0; rr < 16; ++rr) {
        int row = ib + wv * 16 + rr;
        float a1r = a1[row];
        float mr = lrelu(a1r + mhg);
        const int4* p = (const int4*)(adj + (size_t)row * 4096 + jb + lane * 8);
        int4 v0 = p[0], v1 = p[1];
        u32 b = (u32)(v0.x != 0) | ((u32)(v0.y != 0) << 1) | ((u32)(v0.z != 0) << 2) | ((u32)(v0.w != 0) << 3) |
                ((u32)(v1.x != 0) << 4) | ((u32)(v1.y != 0) << 5) | ((u32)(v1.z != 0) << 6) | ((u32)(v1.w != 0) << 7);
        bz[(size_t)row * 512 + (jb >> 3) + lane] = (u8)b;
        float acc = 0.f;
        acc += v0.x ? __expf(lrelu(a1r + A0.x) - mr) : 0.f;
        acc += v0.y ? __expf(lrelu(a1r + A0.y) - mr) : 0.f;
        acc += v0.z ? __expf(lrelu(a1r + A0.z) - mr) : 0.f;
        acc += v0.w ? __expf(lrelu(a1r + A0.w) - mr) : 0.f;
        acc += v1.x ? __expf(lrelu(a1r + A1.x) - mr) : 0.f;
        acc += v1.y ? __expf(lrelu(a1r + A1.y) - mr) : 0.f;
        acc += v1.z ? __expf(lrelu(a1r + A1.z) - mr) : 0.f;
        acc += v1.w ? __expf(lrelu(a1r + A1.w) - mr) : 0.f;
#pragma unroll
        for (int off = 32; off; off >>= 1) acc += __shfl_down(acc, off);
        if (lane == 0) dpart[((size_t)z * 8 + blockIdx.y) * 4096 + row] = acc;
    }
}

__global__ __launch_bounds__(256) void k_dreduce(const float* __restrict__ dpart, float* __restrict__ invd) {
    int i = blockIdx.x * 256 + threadIdx.x;
    if (i < 8192) {
        int z = i >> 12, r = i & 4095;
        float d = 0.f;
#pragma unroll
        for (int s = 0; s < 8; ++s) d += dpart[((size_t)z * 8 + s) * 4096 + r];
        invd[i] = d > 0.f ? 1.f / d : 0.f;
    }
}

// ============ fused: alpha write + msg MFMA (64 rows x 1024 cols, 8 waves, dbuf LDS) ============
__global__ __launch_bounds__(512, 4) void k_flash(const u8* __restrict__ bits,
                                                  const float* __restrict__ avec, const float* __restrict__ Mh,
                                                  const float* __restrict__ invd,
                                                  const u16* __restrict__ WhT, const u16* __restrict__ WiT,
                                                  float* __restrict__ out, float* __restrict__ msgpart) {
    const int z = blockIdx.z;
    const int ib = blockIdx.x * 64;
    const int jb = blockIdx.y * 1024;
    const int tid = threadIdx.x, lane = tid & 63, wv = tid >> 6;
    const u8* bz = bits + (size_t)z * 2097152;
    const float* a1 = avec + z * 8192;
    const float* a2 = a1 + 4096;
    const u16* Pt = z ? WiT : WhT;
    float* alpha = out + 8192 + (size_t)z * 16777216;
    const float mhg = Mh[z];
    const float* inv = invd + z * 4096;

    __shared__ float a2s[1024];
    __shared__ u16 Atile[2 * 64 * 64];
    __shared__ float s_a1[64], s_mr[64], s_inv[64];
    char* Ab = (char*)Atile;

    const int row = wv * 8 + (lane >> 3);
    const int cg = lane & 7;
    const int gr = ib + row;
    const int bbase = jb >> 3;

    {
        float2 v = *(const float2*)(a2 + jb + tid * 2);
        *(float2*)(a2s + tid * 2) = v;
        if (tid < 64) {
            float a = a1[ib + tid];
            s_a1[tid] = a;
            s_mr[tid] = lrelu(a + mhg);
            s_inv[tid] = inv[ib + tid];
        }
    }
    __syncthreads();

    f32x4 acc[4][2];
#pragma unroll
    for (int i = 0; i < 4; i++)
#pragma unroll
        for (int j = 0; j < 2; j++) acc[i][j] = f32x4{0.f, 0.f, 0.f, 0.f};

    float4 stA, stB;
    const float a1r = s_a1[row], mr = s_mr[row], ivr = s_inv[row];
    const int wswz = (row & 7) << 4;

    auto compute_tile = [&](int js, int buf) {
        const int j0 = js * 64;
        u32 byte = bz[(size_t)gr * 512 + bbase + js * 8 + cg];
        const float4 a2a = *(const float4*)(a2s + j0 + cg * 8);
        const float4 a2b = *(const float4*)(a2s + j0 + cg * 8 + 4);
        float av[8] = {a2a.x, a2a.y, a2a.z, a2a.w, a2b.x, a2b.y, a2b.z, a2b.w};
        float al[8];
#pragma unroll
        for (int k = 0; k < 8; ++k) {
            float e = lrelu(a1r + av[k]) - mr;
            float x = ((byte >> k) & 1) ? __expf(e) : 0.f;
            al[k] = x * ivr;
        }
        stA = float4{al[0], al[1], al[2], al[3]};
        stB = float4{al[4], al[5], al[6], al[7]};
        u16 pk[8];
#pragma unroll
        for (int k = 0; k < 8; ++k) pk[k] = f2b(al[k]);
        *(uint4*)(Ab + buf * 8192 + row * 128 + ((cg * 16) ^ wswz)) = *(uint4*)pk;
    };

    compute_tile(0, 0);
    BARRIER_LGKM();

    for (int js = 0; js < 16; ++js) {
        const int j0 = js * 64;
        const int buf = js & 1;
        float* ap = alpha + (size_t)gr * 4096 + jb + j0 + cg * 8;
        *(float4*)ap = stA;
        *(float4*)(ap + 4) = stB;
#pragma unroll
        for (int kh = 0; kh < 2; ++kh) {
            bf16x8 bfr[2];
#pragma unroll
            for (int nf = 0; nf < 2; ++nf) {
                int n = wv * 32 + nf * 16 + (lane & 15);
                bfr[nf] = *(const bf16x8*)(Pt + (size_t)n * 4096 + jb + j0 + kh * 32 + ((lane >> 4) << 3));
            }
#pragma unroll
            for (int mf = 0; mf < 4; ++mf) {
                int row_a = mf * 16 + (lane & 15);
                int kb = kh * 64 + ((lane >> 4) << 4);
                bf16x8 af = *(const bf16x8*)(Ab + buf * 8192 + row_a * 128 + (kb ^ ((row_a & 7) << 4)));
#pragma unroll
                for (int nf = 0; nf < 2; ++nf)
                    acc[mf][nf] = __builtin_amdgcn_mfma_f32_16x16x32_bf16(af, bfr[nf], acc[mf][nf], 0, 0, 0);
            }
        }
        if (js < 15) compute_tile(js + 1, buf ^ 1);
        BARRIER_LGKM();
    }

    float* mp = msgpart + ((size_t)(z * 4 + blockIdx.y) * 4096 + ib) * 256;
#pragma unroll
    for (int mf = 0; mf < 4; ++mf) {
        int r0 = mf * 16 + ((lane >> 4) << 2);
#pragma unroll
        for (int nf = 0; nf < 2; ++nf) {
            int col = wv * 32 + nf * 16 + (lane & 15);
#pragma unroll
            for (int q = 0; q < 4; ++q) mp[(size_t)(r0 + q) * 256 + col] = acc[mf][nf][q];
        }
    }
}

// ============ post: elu(soc+cnt+h_u) + gate ============
__global__ __launch_bounds__(256) void k_post(const float* __restrict__ msgpart, const float* __restrict__ h_u,
                                              const float* __restrict__ q_u,
                                              const float* __restrict__ gate_W, const float* __restrict__ gate_b,
                                              const float* __restrict__ qproj_W, const float* __restrict__ qproj_b,
                                              const float* __restrict__ alpha_q, u16* __restrict__ huo_b) {
    int i = blockIdx.x;
    int n = threadIdx.x;
    float s = 0.f;
#pragma unroll
    for (int p = 0; p < 8; ++p) s += msgpart[((size_t)p * 4096 + i) * 256 + n];
    float v = s + h_u[(size_t)i * 256 + n];
    v = v > 0.f ? v : expm1f(v);
    float q0 = q_u[i * 4 + 0], q1 = q_u[i * 4 + 1], q2 = q_u[i * 4 + 2], q3 = q_u[i * 4 + 3];
    float g = q0 * gate_W[n] + q1 * gate_W[256 + n] + q2 * gate_W[512 + n] + q3 * gate_W[768 + n] + gate_b[n];
    g = 1.f / (1.f + __expf(-g));
    float qp = q0 * qproj_W[n] + q1 * qproj_W[256 + n] + q2 * qproj_W[512 + n] + q3 * qproj_W[768 + n] + qproj_b[n];
    float o = v + alpha_q[0] * g * qp;
    huo_b[(size_t)i * 256 + n] = f2b(o);
}

// ============ pred: gathered GEMM (B=8192, K=512, N=256) + fused r_hat ============
__global__ __launch_bounds__(512) void k_pred(const u16* __restrict__ huo_b, const u16* __restrict__ h_i_b,
                                              const int* __restrict__ uidx, const int* __restrict__ iidx,
                                              const u16* __restrict__ Bt, const float* __restrict__ b1,
                                              const float* __restrict__ W2, const float* __restrict__ b2,
                                              float* __restrict__ out) {
    __shared__ u16 As[64 * 512];
    __shared__ float redL[512];
    const int tid = threadIdx.x, lane = tid & 63, wv = tid >> 6;
    const int bm = blockIdx.x * 64;
    char* Ab = (char*)As;

    {
        const int r = tid >> 3;
        const int uix = uidx[bm + r], iix = iidx[bm + r];
        const int sswz = (r & 7) << 4;
#pragma unroll
        for (int c = 0; c < 8; ++c) {
            int e = c * 64 + (tid & 7) * 8;
            const u16* src = (e < 256) ? (huo_b + (size_t)uix * 256 + e) : (h_i_b + (size_t)iix * 256 + (e - 256));
            uint4 v = *(const uint4*)src;
            *(uint4*)(Ab + r * 1024 + ((e * 2) ^ sswz)) = v;
        }
    }
    __syncthreads();

    const int n0 = wv * 32;
    f32x4 acc[4][2];
#pragma unroll
    for (int i = 0; i < 4; i++)
#pragma unroll
        for (int j = 0; j < 2; j++) acc[i][j] = f32x4{0.f, 0.f, 0.f, 0.f};

    for (int ks = 0; ks < 16; ++ks) {
        bf16x8 bfr[2];
#pragma unroll
        for (int nf = 0; nf < 2; ++nf)
            bfr[nf] = *(const bf16x8*)(Bt + (size_t)(n0 + nf * 16 + (lane & 15)) * 512 + ks * 32 + ((lane >> 4) << 3));
#pragma unroll
        for (int mf = 0; mf < 4; ++mf) {
            int ra = mf * 16 + (lane & 15);
            bf16x8 af = *(const bf16x8*)(Ab + ra * 1024 + ((ks * 64 + ((lane >> 4) << 4)) ^ ((ra & 7) << 4)));
#pragma unroll
            for (int nf = 0; nf < 2; ++nf)
                acc[mf][nf] = __builtin_amdgcn_mfma_f32_16x16x32_bf16(af, bfr[nf], acc[mf][nf], 0, 0, 0);
        }
    }

    float b1v[2], w2v[2];
#pragma unroll
    for (int nf = 0; nf < 2; ++nf) {
        int col = n0 + nf * 16 + (lane & 15);
        b1v[nf] = b1[col];
        w2v[nf] = W2[col];
    }
#pragma unroll
    for (int mf = 0; mf < 4; ++mf) {
#pragma unroll
        for (int q = 0; q < 4; ++q) {
            float val = 0.f;
#pragma unroll
            for (int nf = 0; nf < 2; ++nf) val += fmaxf(acc[mf][nf][q] + b1v[nf], 0.f) * w2v[nf];
#pragma unroll
            for (int off = 1; off < 16; off <<= 1) val += __shfl_xor(val, off);
            if ((lane & 15) == 0) redL[wv * 64 + mf * 16 + ((lane >> 4) << 2) + q] = val;
        }
    }
    __syncthreads();
    if (tid < 64) {
        float r = b2[0];
#pragma unroll
        for (int w = 0; w < 8; ++w) r += redL[w * 64 + tid];
        out[bm + tid] = 1.f + 4.f / (1.f + __expf(-r));
    }
}

extern "C" void kernel_launch(void* const* d_in, const int* in_sizes, int n_in,
                              void* d_out, int out_size, void* d_ws, size_t ws_size,
                              hipStream_t stream) {
    const float* x_u = (const float*)d_in[0];
    const float* x_i = (const float*)d_in[1];
    const int* adjS = (const int*)d_in[2];
    const int* adjC = (const int*)d_in[3];
    const int* uidx = (const int*)d_in[4];
    const int* iidx = (const int*)d_in[5];
    const float* q_u = (const float*)d_in[6];
    const float* user_W = (const float*)d_in[7];
    const float* user_b = (const float*)d_in[8];
    const float* item_W = (const float*)d_in[9];
    const float* item_b = (const float*)d_in[10];
    const float* soc_W = (const float*)d_in[11];
    const float* soc_a = (const float*)d_in[12];
    const float* cnt_W = (const float*)d_in[13];
    const float* cnt_a = (const float*)d_in[14];
    const float* gate_W = (const float*)d_in[15];
    const float* gate_b = (const float*)d_in[16];
    const float* qproj_W = (const float*)d_in[17];
    const float* qproj_b = (const float*)d_in[18];
    const float* alpha_q = (const float*)d_in[19];
    const float* pred_W1 = (const float*)d_in[20];
    const float* pred_b1 = (const float*)d_in[21];
    const float* pred_W2 = (const float*)d_in[22];
    const float* pred_b2 = (const float*)d_in[23];
    float* out = (float*)d_out;

    char* w = (char*)d_ws;
    size_t off = 0;
    auto alloc = [&](size_t bytes) -> void* {
        void* p = w + off;
        off = (off + bytes + 255) & ~(size_t)255;
        return p;
    };
    u16* xu_b = (u16*)alloc((size_t)NU * DD * 2);
    u16* xi_b = (u16*)alloc((size_t)NU * DD * 2);
    u16* uWt = (u16*)alloc(256 * 256 * 2);
    u16* iWt = (u16*)alloc(256 * 256 * 2);
    u16* p1Wt = (u16*)alloc(512 * 256 * 2);
    u16* WusT = (u16*)alloc(256 * 256 * 2);
    u16* WicT = (u16*)alloc(256 * 256 * 2);
    float* b_us = (float*)alloc(256 * 4);
    float* b_ic = (float*)alloc(256 * 4);
    float* uvec = (float*)alloc(4 * 256 * 4);
    float* h_u_f = (float*)alloc((size_t)NU * DD * 4);
    float* h_i_f = (float*)alloc((size_t)NU * DD * 4);
    u16* h_i_b = (u16*)alloc((size_t)NU * DD * 2);
    u16* WhT = (u16*)alloc((size_t)NU * DD * 2);
    u16* WiT = (u16*)alloc((size_t)NU * DD * 2);
    float* avec = (float*)alloc(4 * 4096 * 4);
    float* Mh = (float*)alloc(2 * 4);
    float* dpart = (float*)alloc((size_t)2 * 8 * 4096 * 4);
    float* invd = (float*)alloc((size_t)2 * 4096 * 4);
    u8* bits = (u8*)alloc((size_t)2 * 2097152);
    float* msgpart = (float*)alloc((size_t)2 * 4 * 4096 * 256 * 4);
    u16* huo_b = (u16*)alloc((size_t)NU * DD * 2);
    (void)in_sizes; (void)n_in; (void)out_size; (void)ws_size;

    k_pro<<<1124, 256, 0, stream>>>(x_u, x_i, user_W, item_W, pred_W1, soc_W, soc_a, cnt_W, cnt_a,
                                    user_b, item_b, xu_b, xi_b, uWt, iWt, p1Wt, uvec, WusT, WicT, b_us, b_ic);
    k_gemm4<<<dim3(64, 4, 4), 256, 0, stream>>>(xu_b, xi_b, uWt, iWt, WusT, WicT, user_b, item_b, b_us, b_ic,
                                                h_u_f, h_i_f, h_i_b, WhT, WiT);
    k_gemv_a<<<64, 256, 0, stream>>>(h_u_f, h_i_f, uvec, avec);
    k_maxfinal<<<1, 256, 0, stream>>>(avec, Mh);
    k_scan<<<dim3(64, 8, 2), 256, 0, stream>>>(adjS, adjC, avec, Mh, dpart, bits);
    k_dreduce<<<32, 256, 0, stream>>>(dpart, invd);
    k_flash<<<dim3(64, 4, 2), 512, 0, stream>>>(bits, avec, Mh, invd, WhT, WiT, out, msgpart);
    k_post<<<4096, 256, 0, stream>>>(msgpart, h_u_f, q_u, gate_W, gate_b, qproj_W, qproj_b, alpha_q, huo_b);
    k_pred<<<128, 512, 0, stream>>>(huo_b, h_i_b, uidx, iidx, p1Wt, pred_b1, pred_W2, pred_b2, out);
}

// Round 5
// 189.574 us; speedup vs baseline: 1.5670x; 1.0704x over previous
//
#include <hip/hip_runtime.h>

typedef unsigned short u16;
typedef unsigned int u32;
typedef unsigned char u8;
typedef unsigned long long u64;
typedef float f32x4 __attribute__((ext_vector_type(4)));
typedef __bf16 bf16x8 __attribute__((ext_vector_type(8)));

#define NU 4096
#define DD 256
#define BB 8192

__device__ inline u16 f2b(float f) {
    u32 u = __builtin_bit_cast(u32, f);
    u32 r = (u + 0x7fffu + ((u >> 16) & 1u)) >> 16;
    return (u16)r;
}
__device__ inline float b2f(u16 v) { return __builtin_bit_cast(float, (u32)v << 16); }
__device__ inline float lrelu(float x) { return x > 0.f ? x : 0.2f * x; }
__device__ inline float decmax(u32 e) {
    return __builtin_bit_cast(float, (e >> 31) ? (e & 0x7fffffffu) : ~e);
}

#define BARRIER_LGKM() asm volatile("s_waitcnt lgkmcnt(0)\ns_barrier" ::: "memory")

// ============ prologue: conv(x_u,x_i) + tconv(user,item,pred1) + uvec + wprod ============
__global__ __launch_bounds__(256) void k_pro(
    const float* __restrict__ x_u, const float* __restrict__ x_i,
    const float* __restrict__ user_W, const float* __restrict__ item_W, const float* __restrict__ pred_W1,
    const float* __restrict__ soc_W, const float* __restrict__ soc_a,
    const float* __restrict__ cnt_W, const float* __restrict__ cnt_a,
    const float* __restrict__ user_b, const float* __restrict__ item_b,
    u16* __restrict__ xu_b, u16* __restrict__ xi_b,
    u16* __restrict__ uWt, u16* __restrict__ iWt, u16* __restrict__ p1Wt,
    float* __restrict__ uvec,
    u16* __restrict__ WusT, u16* __restrict__ WicT,
    float* __restrict__ b_us, float* __restrict__ b_ic, u32* __restrict__ MhEnc) {
    __shared__ float t[64][65];
    __shared__ float sa[256];
    const int b = blockIdx.x;
    const int tid = threadIdx.x;

    if (b < 1024) {  // f32 -> bf16 convert
        const float* in = (b < 512) ? x_u : x_i;
        u16* out = (b < 512) ? xu_b : xi_b;
        int i = (b & 511) * 256 + tid;
        const float4 v0 = *(const float4*)(in + (size_t)i * 8);
        const float4 v1 = *(const float4*)(in + (size_t)i * 8 + 4);
        u16 u[8] = {f2b(v0.x), f2b(v0.y), f2b(v0.z), f2b(v0.w),
                    f2b(v1.x), f2b(v1.y), f2b(v1.z), f2b(v1.w)};
        *(uint4*)(out + (size_t)i * 8) = *(uint4*)u;
    } else if (b < 1088) {  // transpose-convert weights
        int j = b - 1024;
        const float* in;
        u16* out;
        int R;
        if (j < 16) { in = user_W; out = uWt; R = 256; }
        else if (j < 32) { in = item_W; out = iWt; R = 256; j -= 16; }
        else { in = pred_W1; out = p1Wt; R = 512; j -= 32; }
        int rb = (j >> 2) * 64, cb = (j & 3) * 64;
        for (int k = 0; k < 16; ++k) {
            int idx = k * 256 + tid;
            int lr = idx >> 6, lc = idx & 63;
            t[lr][lc] = in[(size_t)(rb + lr) * 256 + cb + lc];
        }
        __syncthreads();
        for (int k = 0; k < 16; ++k) {
            int idx = k * 256 + tid;
            int lr = idx >> 6, lc = idx & 63;
            out[(size_t)(cb + lr) * R + rb + lc] = f2b(t[lc][lr]);
        }
    } else if (b < 1092) {  // uvec
        int bb = b - 1088;
        if (bb == 0 && tid < 2) MhEnc[tid] = 0u;
        const float* W = (bb < 2) ? soc_W : cnt_W;
        const float* a = ((bb < 2) ? soc_a : cnt_a) + (bb & 1) * 256;
        int lane = tid & 63, wv = tid >> 6;
        sa[tid] = a[tid];
        __syncthreads();
        for (int rr = 0; rr < 64; ++rr) {
            int in = wv * 64 + rr;
            float4 w4 = *(const float4*)(W + (size_t)in * 256 + lane * 4);
            float acc = w4.x * sa[lane * 4] + w4.y * sa[lane * 4 + 1] + w4.z * sa[lane * 4 + 2] + w4.w * sa[lane * 4 + 3];
#pragma unroll
            for (int off = 32; off; off >>= 1) acc += __shfl_down(acc, off);
            if (lane == 0) uvec[bb * 256 + in] = acc;
        }
    } else {  // wprod: C = A@B (256x256x256), store C^T bf16; bias = bvec@B
        int j = b - 1092;
        int p = j >> 4;
        int tile = j & 15;
        const float* A = p ? item_W : user_W;
        const float* Bw = p ? cnt_W : soc_W;
        const float* bvec = p ? item_b : user_b;
        u16* outT = p ? WicT : WusT;
        float* outb = p ? b_ic : b_us;
        int m0 = (tile >> 2) * 64, n0 = (tile & 3) * 64;
        int m = m0 + (tid >> 4) * 4, n = n0 + (tid & 15) * 4;
        float acc[4][4];
#pragma unroll
        for (int i = 0; i < 4; ++i)
#pragma unroll
            for (int k = 0; k < 4; ++k) acc[i][k] = 0.f;
        for (int k0 = 0; k0 < 256; k0 += 4) {
            float aa[4][4], bb2[4][4];
#pragma unroll
            for (int i = 0; i < 4; ++i) {
                float4 v = *(const float4*)(A + (size_t)(m + i) * 256 + k0);
                aa[i][0] = v.x; aa[i][1] = v.y; aa[i][2] = v.z; aa[i][3] = v.w;
            }
#pragma unroll
            for (int k = 0; k < 4; ++k) {
                float4 v = *(const float4*)(Bw + (size_t)(k0 + k) * 256 + n);
                bb2[k][0] = v.x; bb2[k][1] = v.y; bb2[k][2] = v.z; bb2[k][3] = v.w;
            }
#pragma unroll
            for (int i = 0; i < 4; ++i)
#pragma unroll
                for (int k = 0; k < 4; ++k)
#pragma unroll
                    for (int jj = 0; jj < 4; ++jj) acc[i][jj] += aa[i][k] * bb2[k][jj];
        }
#pragma unroll
        for (int i = 0; i < 4; ++i)
#pragma unroll
            for (int jj = 0; jj < 4; ++jj) outT[(size_t)(n + jj) * 256 + m + i] = f2b(acc[i][jj]);
        if (tile >> 2 == 0 && tid < 64) {
            int nn = n0 + tid;
            float s = 0.f;
            for (int k = 0; k < 256; ++k) s += bvec[k] * Bw[(size_t)k * 256 + nn];
            outb[nn] = s;
        }
    }
}

// ============ z=4 feature GEMMs: h_u, h_i(+bf16), WhT, WiT ============
__global__ __launch_bounds__(256) void k_gemm4(
    const u16* __restrict__ xu_b, const u16* __restrict__ xi_b,
    const u16* __restrict__ uWt, const u16* __restrict__ iWt,
    const u16* __restrict__ WusT, const u16* __restrict__ WicT,
    const float* __restrict__ user_b, const float* __restrict__ item_b,
    const float* __restrict__ b_us, const float* __restrict__ b_ic,
    float* __restrict__ h_u_f, float* __restrict__ h_i_f, u16* __restrict__ h_i_b,
    u16* __restrict__ WhT, u16* __restrict__ WiT) {
    const int z = blockIdx.z;
    const int M = 4096, N = 256, K = 256;
    const u16* A = (z == 0 || z == 2) ? xu_b : xi_b;
    const u16* Bt = (z == 0) ? uWt : (z == 1) ? iWt : (z == 2) ? WusT : WicT;
    const float* bias = (z == 0) ? user_b : (z == 1) ? item_b : (z == 2) ? b_us : b_ic;
    float* Cf = (z == 0) ? h_u_f : (z == 1) ? h_i_f : nullptr;
    u16* Cb = (z == 1) ? h_i_b : nullptr;
    u16* Cbt = (z == 2) ? WhT : (z == 3) ? WiT : nullptr;

    __shared__ u16 As[64 * 64];
    __shared__ u16 Bs[64 * 64];
    const int tid = threadIdx.x;
    const int lane = tid & 63, wv = tid >> 6;
    const int bm = blockIdx.x * 64, bn = blockIdx.y * 64;
    const int wm = (wv >> 1) * 32, wn = (wv & 1) * 32;
    f32x4 acc[2][2];
#pragma unroll
    for (int i = 0; i < 2; i++)
#pragma unroll
        for (int j = 0; j < 2; j++) acc[i][j] = f32x4{0.f, 0.f, 0.f, 0.f};

    char* Ab = (char*)As;
    char* Bb = (char*)Bs;
    const int r = tid >> 2;
    const int ib0 = (tid & 3) * 32;
    const int swz = (r & 7) << 4;

    for (int k0 = 0; k0 < K; k0 += 64) {
        const uint4* ga = (const uint4*)(A + (size_t)(bm + r) * K + k0 + (ib0 >> 1));
        const uint4* gb = (const uint4*)(Bt + (size_t)(bn + r) * K + k0 + (ib0 >> 1));
        uint4 va0 = ga[0], va1 = ga[1];
        uint4 vb0 = gb[0], vb1 = gb[1];
        __syncthreads();
        *(uint4*)(Ab + r * 128 + ((ib0) ^ swz)) = va0;
        *(uint4*)(Ab + r * 128 + ((ib0 + 16) ^ swz)) = va1;
        *(uint4*)(Bb + r * 128 + ((ib0) ^ swz)) = vb0;
        *(uint4*)(Bb + r * 128 + ((ib0 + 16) ^ swz)) = vb1;
        __syncthreads();
#pragma unroll
        for (int kh = 0; kh < 2; ++kh) {
            bf16x8 af[2], bfr[2];
#pragma unroll
            for (int mf = 0; mf < 2; ++mf) {
                int row = wm + mf * 16 + (lane & 15);
                int kb = kh * 64 + ((lane >> 4) << 4);
                af[mf] = *(const bf16x8*)(Ab + row * 128 + (kb ^ ((row & 7) << 4)));
            }
#pragma unroll
            for (int nf = 0; nf < 2; ++nf) {
                int row = wn + nf * 16 + (lane & 15);
                int kb = kh * 64 + ((lane >> 4) << 4);
                bfr[nf] = *(const bf16x8*)(Bb + row * 128 + (kb ^ ((row & 7) << 4)));
            }
#pragma unroll
            for (int mf = 0; mf < 2; ++mf)
#pragma unroll
                for (int nf = 0; nf < 2; ++nf)
                    acc[mf][nf] = __builtin_amdgcn_mfma_f32_16x16x32_bf16(af[mf], bfr[nf], acc[mf][nf], 0, 0, 0);
        }
    }
#pragma unroll
    for (int mf = 0; mf < 2; ++mf) {
#pragma unroll
        for (int nf = 0; nf < 2; ++nf) {
            int col = bn + wn + nf * 16 + (lane & 15);
            int row0 = bm + wm + mf * 16 + ((lane >> 4) << 2);
            float bv = bias[col];
            float v[4];
#pragma unroll
            for (int q = 0; q < 4; ++q) {
                float x = acc[mf][nf][q] + bv;
                v[q] = x;
                if (Cf) Cf[(size_t)(row0 + q) * N + col] = x;
                if (Cb) Cb[(size_t)(row0 + q) * N + col] = f2b(x);
            }
            if (Cbt) {
                uint2 p;
                p.x = (u32)f2b(v[0]) | ((u32)f2b(v[1]) << 16);
                p.y = (u32)f2b(v[2]) | ((u32)f2b(v[3]) << 16);
                *(uint2*)(Cbt + (size_t)col * M + row0) = p;
            }
        }
    }
}

// ============ a-vector GEMVs + fused a2-max (atomicMax on monotonic-encoded u32) ============
__global__ __launch_bounds__(256) void k_gemv_a(const float* __restrict__ h_u, const float* __restrict__ h_i,
                                                const float* __restrict__ uvec, float* __restrict__ avec,
                                                u32* __restrict__ MhEnc) {
    int tid = threadIdx.x, lane = tid & 63, wv = tid >> 6;
    int ib = blockIdx.x * 64;
    const float* H = (wv == 3) ? h_i : h_u;
    const float* u = uvec + wv * 256;
    float4 u4 = *(const float4*)(u + lane * 4);
    float runm = -1e30f;
    for (int rr = 0; rr < 64; ++rr) {
        int row = ib + rr;
        float4 h4 = *(const float4*)(H + (size_t)row * 256 + lane * 4);
        float acc = h4.x * u4.x + h4.y * u4.y + h4.z * u4.z + h4.w * u4.w;
#pragma unroll
        for (int off = 32; off; off >>= 1) acc += __shfl_down(acc, off);
        if (lane == 0) {
            avec[wv * 4096 + row] = acc;
            runm = fmaxf(runm, acc);
        }
    }
    if (lane == 0 && (wv & 1)) {
        u32 b = __builtin_bit_cast(u32, runm);
        u32 e = (b >> 31) ? ~b : (b | 0x80000000u);
        atomicMax(&MhEnc[wv >> 1], e);
    }
}

// ============ denom scan + bit-pack adjacency (flash-friendly layout) ============
__global__ __launch_bounds__(256) void k_scan(const int* __restrict__ adjS, const int* __restrict__ adjC,
                                              const float* __restrict__ avec, const u32* __restrict__ MhEnc,
                                              float* __restrict__ dpart, u8* __restrict__ bits) {
    int z = blockIdx.z;
    const int* adj = z ? adjC : adjS;
    const float* a1 = avec + z * 8192;
    const float* a2 = a1 + 4096;
    u8* bz = bits + (size_t)z * 2097152;
    float mhg = decmax(MhEnc[z]);
    int ib = blockIdx.x * 64, jb = blockIdx.y * 512;
    int lane = threadIdx.x & 63, wv = threadIdx.x >> 6;
    float4 A0 = *(const float4*)(a2 + jb + lane * 8);
    float4 A1 = *(const float4*)(a2 + jb + lane * 8 + 4);
    // bit-byte addr: row*512 + (j>>9)*64 + ((j>>3)&7)*8 + ((j>>6)&7)
    const int boff = blockIdx.y * 64 + (lane & 7) * 8 + (lane >> 3);
    for (int rr = 0; rr < 16; ++rr) {
        int row = ib + wv * 16 + rr;
        float a1r = a1[row];
        float mr = lrelu(a1r + mhg);
        const int4* p = (const int4*)(adj + (size_t)row * 4096 + jb + lane * 8);
        int4 v0 = p[0], v1 = p[1];
        u32 b = (u32)(v0.x != 0) | ((u32)(v0.y != 0) << 1) | ((u32)(v0.z != 0) << 2) | ((u32)(v0.w != 0) << 3) |
                ((u32)(v1.x != 0) << 4) | ((u32)(v1.y != 0) << 5) | ((u32)(v1.z != 0) << 6) | ((u32)(v1.w != 0) << 7);
        bz[(size_t)row * 512 + boff] = (u8)b;
        float acc = 0.f;
        acc += v0.x ? __expf(lrelu(a1r + A0.x) - mr) : 0.f;
        acc += v0.y ? __expf(lrelu(a1r + A0.y) - mr) : 0.f;
        acc += v0.z ? __expf(lrelu(a1r + A0.z) - mr) : 0.f;
        acc += v0.w ? __expf(lrelu(a1r + A0.w) - mr) : 0.f;
        acc += v1.x ? __expf(lrelu(a1r + A1.x) - mr) : 0.f;
        acc += v1.y ? __expf(lrelu(a1r + A1.y) - mr) : 0.f;
        acc += v1.z ? __expf(lrelu(a1r + A1.z) - mr) : 0.f;
        acc += v1.w ? __expf(lrelu(a1r + A1.w) - mr) : 0.f;
#pragma unroll
        for (int off = 32; off; off >>= 1) acc += __shfl_down(acc, off);
        if (lane == 0) dpart[((size_t)z * 8 + blockIdx.y) * 4096 + row] = acc;
    }
}

// ============ fused: alpha write + msg MFMA (64 rows x 512 cols, 8 waves, dbuf LDS, Pt prefetch) ============
__global__ __launch_bounds__(512, 4) void k_flash(const u8* __restrict__ bits,
                                                  const float* __restrict__ avec, const u32* __restrict__ MhEnc,
                                                  const float* __restrict__ dpart,
                                                  const u16* __restrict__ WhT, const u16* __restrict__ WiT,
                                                  float* __restrict__ out, u16* __restrict__ msgpart) {
    const int z = blockIdx.z;
    const int ib = blockIdx.x * 64;
    const int jb = blockIdx.y * 512;
    const int tid = threadIdx.x, lane = tid & 63, wv = tid >> 6;
    const u8* bz = bits + (size_t)z * 2097152;
    const float* a1 = avec + z * 8192;
    const float* a2 = a1 + 4096;
    const u16* Pt = z ? WiT : WhT;
    float* alpha = out + 8192 + (size_t)z * 16777216;

    __shared__ float a2s[512];
    __shared__ u16 Atile[2 * 64 * 64];
    __shared__ float s_a1[64], s_mr[64], s_inv[64];
    char* Ab = (char*)Atile;

    a2s[tid] = a2[jb + tid];
    if (tid < 64) {
        float a = a1[ib + tid];
        float mhg = decmax(MhEnc[z]);
        s_a1[tid] = a;
        s_mr[tid] = lrelu(a + mhg);
        float d = 0.f;
#pragma unroll
        for (int s = 0; s < 8; ++s) d += dpart[((size_t)(z * 8 + s)) * 4096 + ib + tid];
        s_inv[tid] = d > 0.f ? 1.f / d : 0.f;
    }
    __syncthreads();

    const int row = wv * 8 + (lane >> 3);
    const int cg = lane & 7;
    const int gr = ib + row;
    const u64 b64 = *(const u64*)(bz + (size_t)gr * 512 + (jb >> 9) * 64 + cg * 8);
    const float a1r = s_a1[row], mr = s_mr[row], ivr = s_inv[row];
    const int wswz = (row & 7) << 4;

    const u16* ptb0 = Pt + (size_t)(wv * 32 + (lane & 15)) * 4096 + jb + ((lane >> 4) << 3);
    const u16* ptb1 = ptb0 + (size_t)16 * 4096;

    f32x4 acc[4][2];
#pragma unroll
    for (int i = 0; i < 4; i++)
#pragma unroll
        for (int j = 0; j < 2; j++) acc[i][j] = f32x4{0.f, 0.f, 0.f, 0.f};

    float al[8];
    auto compute_al = [&](int js, int buf) {
        const float4 a2a = *(const float4*)(a2s + js * 64 + cg * 8);
        const float4 a2b = *(const float4*)(a2s + js * 64 + cg * 8 + 4);
        u32 byte = (u32)(b64 >> (js * 8)) & 0xffu;
        float av[8] = {a2a.x, a2a.y, a2a.z, a2a.w, a2b.x, a2b.y, a2b.z, a2b.w};
#pragma unroll
        for (int k = 0; k < 8; ++k) {
            float e = lrelu(a1r + av[k]) - mr;
            al[k] = ((byte >> k) & 1) ? __expf(e) * ivr : 0.f;
        }
        u16 pk[8];
#pragma unroll
        for (int k = 0; k < 8; ++k) pk[k] = f2b(al[k]);
        *(uint4*)(Ab + buf * 8192 + row * 128 + ((cg * 16) ^ wswz)) = *(uint4*)pk;
    };

    compute_al(0, 0);
    BARRIER_LGKM();

    bf16x8 bcur[2][2], bnxt[2][2];
#pragma unroll
    for (int kh = 0; kh < 2; ++kh) {
        bcur[kh][0] = *(const bf16x8*)(ptb0 + kh * 32);
        bcur[kh][1] = *(const bf16x8*)(ptb1 + kh * 32);
    }

    for (int js = 0; js < 8; ++js) {
        const int buf = js & 1;
        // alpha store for tile js (values in al[]), overlaps with MFMA
        {
            float4 sA = {al[0], al[1], al[2], al[3]};
            float4 sB = {al[4], al[5], al[6], al[7]};
            float* ap = alpha + (size_t)gr * 4096 + jb + js * 64 + cg * 8;
            *(float4*)ap = sA;
            *(float4*)(ap + 4) = sB;
        }
        // prefetch Pt for tile js+1 (issued before MFMA, stays in flight across barrier)
        if (js < 7) {
#pragma unroll
            for (int kh = 0; kh < 2; ++kh) {
                bnxt[kh][0] = *(const bf16x8*)(ptb0 + (js + 1) * 64 + kh * 32);
                bnxt[kh][1] = *(const bf16x8*)(ptb1 + (js + 1) * 64 + kh * 32);
            }
        }
        // MFMA on tile js
#pragma unroll
        for (int kh = 0; kh < 2; ++kh) {
#pragma unroll
            for (int mf = 0; mf < 4; ++mf) {
                int ra = mf * 16 + (lane & 15);
                int kb = kh * 64 + ((lane >> 4) << 4);
                bf16x8 af = *(const bf16x8*)(Ab + buf * 8192 + ra * 128 + (kb ^ ((ra & 7) << 4)));
#pragma unroll
                for (int nf = 0; nf < 2; ++nf)
                    acc[mf][nf] = __builtin_amdgcn_mfma_f32_16x16x32_bf16(af, bcur[kh][nf], acc[mf][nf], 0, 0, 0);
            }
        }
        // compute tile js+1 into other LDS buffer
        if (js < 7) compute_al(js + 1, buf ^ 1);
        BARRIER_LGKM();
        if (js < 7) {
#pragma unroll
            for (int kh = 0; kh < 2; ++kh) {
                bcur[kh][0] = bnxt[kh][0];
                bcur[kh][1] = bnxt[kh][1];
            }
        }
    }

    u16* mp = msgpart + ((size_t)(z * 8 + blockIdx.y) * 4096 + ib) * 256;
#pragma unroll
    for (int mf = 0; mf < 4; ++mf) {
        int r0 = mf * 16 + ((lane >> 4) << 2);
#pragma unroll
        for (int nf = 0; nf < 2; ++nf) {
            int col = wv * 32 + nf * 16 + (lane & 15);
#pragma unroll
            for (int q = 0; q < 4; ++q) mp[(size_t)(r0 + q) * 256 + col] = f2b(acc[mf][nf][q]);
        }
    }
}

// ============ post: elu(soc+cnt+h_u) + gate ============
__global__ __launch_bounds__(256) void k_post(const u16* __restrict__ msgpart, const float* __restrict__ h_u,
                                              const float* __restrict__ q_u,
                                              const float* __restrict__ gate_W, const float* __restrict__ gate_b,
                                              const float* __restrict__ qproj_W, const float* __restrict__ qproj_b,
                                              const float* __restrict__ alpha_q, u16* __restrict__ huo_b) {
    int i = blockIdx.x;
    int n = threadIdx.x;
    float s = 0.f;
#pragma unroll
    for (int p = 0; p < 16; ++p) s += b2f(msgpart[((size_t)p * 4096 + i) * 256 + n]);
    float v = s + h_u[(size_t)i * 256 + n];
    v = v > 0.f ? v : expm1f(v);
    float q0 = q_u[i * 4 + 0], q1 = q_u[i * 4 + 1], q2 = q_u[i * 4 + 2], q3 = q_u[i * 4 + 3];
    float g = q0 * gate_W[n] + q1 * gate_W[256 + n] + q2 * gate_W[512 + n] + q3 * gate_W[768 + n] + gate_b[n];
    g = 1.f / (1.f + __expf(-g));
    float qp = q0 * qproj_W[n] + q1 * qproj_W[256 + n] + q2 * qproj_W[512 + n] + q3 * qproj_W[768 + n] + qproj_b[n];
    float o = v + alpha_q[0] * g * qp;
    huo_b[(size_t)i * 256 + n] = f2b(o);
}

// ============ pred: gathered GEMM (B=8192, K=512, N=256) + fused r_hat ============
__global__ __launch_bounds__(512) void k_pred(const u16* __restrict__ huo_b, const u16* __restrict__ h_i_b,
                                              const int* __restrict__ uidx, const int* __restrict__ iidx,
                                              const u16* __restrict__ Bt, const float* __restrict__ b1,
                                              const float* __restrict__ W2, const float* __restrict__ b2,
                                              float* __restrict__ out) {
    __shared__ u16 As[64 * 512];
    __shared__ float redL[512];
    const int tid = threadIdx.x, lane = tid & 63, wv = tid >> 6;
    const int bm = blockIdx.x * 64;
    char* Ab = (char*)As;

    {
        const int r = tid >> 3;
        const int uix = uidx[bm + r], iix = iidx[bm + r];
        const int sswz = (r & 7) << 4;
#pragma unroll
        for (int c = 0; c < 8; ++c) {
            int e = c * 64 + (tid & 7) * 8;
            const u16* src = (e < 256) ? (huo_b + (size_t)uix * 256 + e) : (h_i_b + (size_t)iix * 256 + (e - 256));
            uint4 v = *(const uint4*)src;
            *(uint4*)(Ab + r * 1024 + ((e * 2) ^ sswz)) = v;
        }
    }
    __syncthreads();

    const int n0 = wv * 32;
    f32x4 acc[4][2];
#pragma unroll
    for (int i = 0; i < 4; i++)
#pragma unroll
        for (int j = 0; j < 2; j++) acc[i][j] = f32x4{0.f, 0.f, 0.f, 0.f};

    for (int ks = 0; ks < 16; ++ks) {
        bf16x8 bfr[2];
#pragma unroll
        for (int nf = 0; nf < 2; ++nf)
            bfr[nf] = *(const bf16x8*)(Bt + (size_t)(n0 + nf * 16 + (lane & 15)) * 512 + ks * 32 + ((lane >> 4) << 3));
#pragma unroll
        for (int mf = 0; mf < 4; ++mf) {
            int ra = mf * 16 + (lane & 15);
            bf16x8 af = *(const bf16x8*)(Ab + ra * 1024 + ((ks * 64 + ((lane >> 4) << 4)) ^ ((ra & 7) << 4)));
#pragma unroll
            for (int nf = 0; nf < 2; ++nf)
                acc[mf][nf] = __builtin_amdgcn_mfma_f32_16x16x32_bf16(af, bfr[nf], acc[mf][nf], 0, 0, 0);
        }
    }

    float b1v[2], w2v[2];
#pragma unroll
    for (int nf = 0; nf < 2; ++nf) {
        int col = n0 + nf * 16 + (lane & 15);
        b1v[nf] = b1[col];
        w2v[nf] = W2[col];
    }
#pragma unroll
    for (int mf = 0; mf < 4; ++mf) {
#pragma unroll
        for (int q = 0; q < 4; ++q) {
            float val = 0.f;
#pragma unroll
            for (int nf = 0; nf < 2; ++nf) val += fmaxf(acc[mf][nf][q] + b1v[nf], 0.f) * w2v[nf];
#pragma unroll
            for (int off = 1; off < 16; off <<= 1) val += __shfl_xor(val, off);
            if ((lane & 15) == 0) redL[wv * 64 + mf * 16 + ((lane >> 4) << 2) + q] = val;
        }
    }
    __syncthreads();
    if (tid < 64) {
        float r = b2[0];
#pragma unroll
        for (int w = 0; w < 8; ++w) r += redL[w * 64 + tid];
        out[bm + tid] = 1.f + 4.f / (1.f + __expf(-r));
    }
}

extern "C" void kernel_launch(void* const* d_in, const int* in_sizes, int n_in,
                              void* d_out, int out_size, void* d_ws, size_t ws_size,
                              hipStream_t stream) {
    const float* x_u = (const float*)d_in[0];
    const float* x_i = (const float*)d_in[1];
    const int* adjS = (const int*)d_in[2];
    const int* adjC = (const int*)d_in[3];
    const int* uidx = (const int*)d_in[4];
    const int* iidx = (const int*)d_in[5];
    const float* q_u = (const float*)d_in[6];
    const float* user_W = (const float*)d_in[7];
    const float* user_b = (const float*)d_in[8];
    const float* item_W = (const float*)d_in[9];
    const float* item_b = (const float*)d_in[10];
    const float* soc_W = (const float*)d_in[11];
    const float* soc_a = (const float*)d_in[12];
    const float* cnt_W = (const float*)d_in[13];
    const float* cnt_a = (const float*)d_in[14];
    const float* gate_W = (const float*)d_in[15];
    const float* gate_b = (const float*)d_in[16];
    const float* qproj_W = (const float*)d_in[17];
    const float* qproj_b = (const float*)d_in[18];
    const float* alpha_q = (const float*)d_in[19];
    const float* pred_W1 = (const float*)d_in[20];
    const float* pred_b1 = (const float*)d_in[21];
    const float* pred_W2 = (const float*)d_in[22];
    const float* pred_b2 = (const float*)d_in[23];
    float* out = (float*)d_out;

    char* w = (char*)d_ws;
    size_t off = 0;
    auto alloc = [&](size_t bytes) -> void* {
        void* p = w + off;
        off = (off + bytes + 255) & ~(size_t)255;
        return p;
    };
    u16* xu_b = (u16*)alloc((size_t)NU * DD * 2);
    u16* xi_b = (u16*)alloc((size_t)NU * DD * 2);
    u16* uWt = (u16*)alloc(256 * 256 * 2);
    u16* iWt = (u16*)alloc(256 * 256 * 2);
    u16* p1Wt = (u16*)alloc(512 * 256 * 2);
    u16* WusT = (u16*)alloc(256 * 256 * 2);
    u16* WicT = (u16*)alloc(256 * 256 * 2);
    float* b_us = (float*)alloc(256 * 4);
    float* b_ic = (float*)alloc(256 * 4);
    float* uvec = (float*)alloc(4 * 256 * 4);
    float* h_u_f = (float*)alloc((size_t)NU * DD * 4);
    float* h_i_f = (float*)alloc((size_t)NU * DD * 4);
    u16* h_i_b = (u16*)alloc((size_t)NU * DD * 2);
    u16* WhT = (u16*)alloc((size_t)NU * DD * 2);
    u16* WiT = (u16*)alloc((size_t)NU * DD * 2);
    float* avec = (float*)alloc(4 * 4096 * 4);
    u32* MhEnc = (u32*)alloc(2 * 4);
    float* dpart = (float*)alloc((size_t)2 * 8 * 4096 * 4);
    u8* bits = (u8*)alloc((size_t)2 * 2097152);
    u16* msgpart = (u16*)alloc((size_t)16 * 4096 * 256 * 2);
    u16* huo_b = (u16*)alloc((size_t)NU * DD * 2);
    (void)in_sizes; (void)n_in; (void)out_size; (void)ws_size;

    k_pro<<<1124, 256, 0, stream>>>(x_u, x_i, user_W, item_W, pred_W1, soc_W, soc_a, cnt_W, cnt_a,
                                    user_b, item_b, xu_b, xi_b, uWt, iWt, p1Wt, uvec, WusT, WicT,
                                    b_us, b_ic, MhEnc);
    k_gemm4<<<dim3(64, 4, 4), 256, 0, stream>>>(xu_b, xi_b, uWt, iWt, WusT, WicT, user_b, item_b, b_us, b_ic,
                                                h_u_f, h_i_f, h_i_b, WhT, WiT);
    k_gemv_a<<<64, 256, 0, stream>>>(h_u_f, h_i_f, uvec, avec, MhEnc);
    k_scan<<<dim3(64, 8, 2), 256, 0, stream>>>(adjS, adjC, avec, MhEnc, dpart, bits);
    k_flash<<<dim3(64, 8, 2), 512, 0, stream>>>(bits, avec, MhEnc, dpart, WhT, WiT, out, msgpart);
    k_post<<<4096, 256, 0, stream>>>(msgpart, h_u_f, q_u, gate_W, gate_b, qproj_W, qproj_b, alpha_q, huo_b);
    k_pred<<<128, 512, 0, stream>>>(huo_b, h_i_b, uidx, iidx, p1Wt, pred_b1, pred_W2, pred_b2, out);
}